// Round 7
// baseline (202.997 us; speedup 1.0000x reference)
//
#include <hip/hip_runtime.h>
#include <math.h>

#define HDIM 2048
#define WDIM 2048
#define NPIX (HDIM*WDIM)
#define OUTW 2038          /* valid conv output size: 2048-10 */

#define C1F 6.5025f        /* (0.01*255)^2 */
#define C2F 58.5225f       /* (0.03*255)^2 */

constexpr int TH   = 64, TW = 32;  // conv output tile
constexpr int HT_R = 80;           // HT row stride: [arr][col][row]
constexpr int HT_A = 32 * HT_R;    // 2560 f16 per array
constexpr int NCH  = 4;            // mu1, mu2, (p^2+t^2)/4, p*t
constexpr int NBLK2 = 8192;        // conv blocks
constexpr int PR9  = 9 * 1024;     // 9 pointwise channels x 1024 stream blocks
constexpr size_t QBYTES = (size_t)8 * NPIX;                 // u8 quant: 4b x 2img
constexpr size_t WS_NEEDED = QBYTES + (size_t)(PR9 + NBLK2) * 4;

// fallback (round-6 fused) constants
constexpr int IQ_S = 56;
constexpr int IN_R = 80;
constexpr int IQ_H = IN_R * IQ_S;
constexpr int NBLK = 8192;

struct GaussW { float g[11]; };

typedef _Float16 half8 __attribute__((ext_vector_type(8)));
typedef float    f32x4 __attribute__((ext_vector_type(4)));
typedef float    f32x2 __attribute__((ext_vector_type(2)));

// quant: bit-exact vs reference sequence. (clip(x)+1)*0.5 then *255 ==
// (clip(x)+1)*127.5; trunc == floor for v >= 0. Must stay add-then-mul.
__device__ __forceinline__ float quant_u8f(float x) {
    float c = __builtin_amdgcn_fmed3f(x, -1.0f, 1.0f);
    return truncf((c + 1.0f) * 127.5f);
}
__device__ __forceinline__ f32x2 quant2(f32x2 x) {
    f32x2 c = { __builtin_amdgcn_fmed3f(x.x, -1.0f, 1.0f),
                __builtin_amdgcn_fmed3f(x.y, -1.0f, 1.0f) };
    f32x2 v = (c + 1.0f) * 127.5f;     // pk_add then pk_mul: matches reference
    return { truncf(v.x), truncf(v.y) };
}
__device__ __forceinline__ unsigned pk2(float a, float b) {
    return __builtin_bit_cast(unsigned, __builtin_amdgcn_cvt_pkrtz(a, b));
}
__device__ __forceinline__ unsigned pack4_u8(const float* v) {
#if __has_builtin(__builtin_amdgcn_cvt_pk_u8_f32)
    unsigned r = 0;
    r = __builtin_amdgcn_cvt_pk_u8_f32(v[0], 0, r);
    r = __builtin_amdgcn_cvt_pk_u8_f32(v[1], 1, r);
    r = __builtin_amdgcn_cvt_pk_u8_f32(v[2], 2, r);
    r = __builtin_amdgcn_cvt_pk_u8_f32(v[3], 3, r);
    return r;
#else
    return ((unsigned)(int)v[0]) | (((unsigned)(int)v[1]) << 8) |
           (((unsigned)(int)v[2]) << 16) | (((unsigned)(int)v[3]) << 24);
#endif
}
// 8 packed u8 (2 dwords, little-endian col order) -> half8 (exact)
__device__ __forceinline__ half8 unpack_u8x8(unsigned lo, unsigned hi) {
    union { unsigned u[4]; half8 h; } r;
    r.u[0] = pk2((float)(lo & 0xffu),         (float)((lo >> 8)  & 0xffu));
    r.u[1] = pk2((float)((lo >> 16) & 0xffu), (float)((lo >> 24) & 0xffu));
    r.u[2] = pk2((float)(hi & 0xffu),         (float)((hi >> 8)  & 0xffu));
    r.u[3] = pk2((float)((hi >> 16) & 0xffu), (float)((hi >> 24) & 0xffu));
    return r.h;
}

// ---------------------------------------------------------------------------
// Kernel 1 (round 14): streaming pointwise stats + u8 quantize.
//   Each thread owns a 16-row x 4-col strip; previous row's dd held in regs
//   so gx needs no re-read (one extra boundary row per segment, +6% fetch on
//   that row only). Perfectly coalesced float4 reads, uint writes.
//   Memory-bound by design: 128 MB R + 33.5 MB W at streaming BW.
// Channels: 0:l1 1:gxH 2:gyW 3:relu 4:sp 5:st 6:spp 7:stt 8:su8
// ---------------------------------------------------------------------------
__global__ __launch_bounds__(256, 6) void amsr2_stream(
        const float* __restrict__ pred, const float* __restrict__ targ,
        unsigned char* __restrict__ qbuf, float* __restrict__ pr)
{
    __shared__ float sred[16][9];
    const int g   = blockIdx.x * 256 + threadIdx.x;
    const int b   = g >> 16;           // 65536 threads per batch (256 blocks)
    const int rem = g & 65535;
    const int seg = rem >> 9;          // 0..127 row-segment, block-uniform
    const int cg  = rem & 511;         // col-group (4 floats)
    const int r_start = seg * 16;
    const bool hasR = (cg != 511);

    const float* pp = pred + (size_t)b * NPIX + (size_t)r_start * WDIM + cg * 4;
    const float* tt = targ + (size_t)b * NPIX + (size_t)r_start * WDIM + cg * 4;
    unsigned char* qo = qbuf + (size_t)(b * 2) * NPIX + (size_t)r_start * WDIM + cg * 4;

    float s0 = 0.f, s1 = 0.f, s2 = 0.f, s3 = 0.f;
    f32x2 s4v = {0,0}, s5v = {0,0}, s6v = {0,0}, s7v = {0,0}, s8v = {0,0};
    f32x2 pd01 = {0,0}, pd23 = {0,0};

#pragma unroll 4
    for (int it = 0; it < 16; ++it) {
        float4 a4 = *(const float4*)pp;
        float4 b4 = *(const float4*)tt;
        float p5 = 0.f, t5 = 0.f;
        if (hasR) { p5 = pp[4]; t5 = tt[4]; }

        f32x2 a01 = {a4.x, a4.y}, a23 = {a4.z, a4.w};
        f32x2 b01 = {b4.x, b4.y}, b23 = {b4.z, b4.w};
        f32x2 dd01 = a01 - b01, dd23 = a23 - b23;
        float dd4 = p5 - t5;

        // l1
        s0 += fabsf(dd01.x); s0 += fabsf(dd01.y);
        s0 += fabsf(dd23.x); s0 += fabsf(dd23.y);
        // gx (row r-1 vs r) via register-carried previous dd
        if (it > 0) {
            s1 += fabsf(pd01.x - dd01.x); s1 += fabsf(pd01.y - dd01.y);
            s1 += fabsf(pd23.x - dd23.x); s1 += fabsf(pd23.y - dd23.y);
        }
        // gy within row
        s2 += fabsf(dd01.x - dd01.y); s2 += fabsf(dd01.y - dd23.x);
        s2 += fabsf(dd23.x - dd23.y);
        if (hasR) s2 += fabsf(dd23.y - dd4);
        // range penalty
        s3 += fmaxf(fabsf(a4.x) - 1.0f, 0.0f);
        s3 += fmaxf(fabsf(a4.y) - 1.0f, 0.0f);
        s3 += fmaxf(fabsf(a4.z) - 1.0f, 0.0f);
        s3 += fmaxf(fabsf(a4.w) - 1.0f, 0.0f);
        // packed sums / sumsqs
        s4v += a01; s4v += a23;
        s5v += b01; s5v += b23;
        s6v += a01 * a01; s6v += a23 * a23;
        s7v += b01 * b01; s7v += b23 * b23;
        // quant + u8 mse + store
        f32x2 qp01 = quant2(a01), qp23 = quant2(a23);
        f32x2 qt01 = quant2(b01), qt23 = quant2(b23);
        f32x2 qd01 = qp01 - qt01, qd23 = qp23 - qt23;
        s8v += qd01 * qd01; s8v += qd23 * qd23;
        float qpv[4] = {qp01.x, qp01.y, qp23.x, qp23.y};
        float qtv[4] = {qt01.x, qt01.y, qt23.x, qt23.y};
        *(unsigned*)qo          = pack4_u8(qpv);
        *(unsigned*)(qo + NPIX) = pack4_u8(qtv);

        pd01 = dd01; pd23 = dd23;
        pp += WDIM; tt += WDIM; qo += WDIM;
    }
    // segment-boundary gx row (block-uniform branch)
    if (seg != 127) {
        float4 a4 = *(const float4*)pp;
        float4 b4 = *(const float4*)tt;
        f32x2 dd01 = f32x2{a4.x, a4.y} - f32x2{b4.x, b4.y};
        f32x2 dd23 = f32x2{a4.z, a4.w} - f32x2{b4.z, b4.w};
        s1 += fabsf(pd01.x - dd01.x); s1 += fabsf(pd01.y - dd01.y);
        s1 += fabsf(pd23.x - dd23.x); s1 += fabsf(pd23.y - dd23.y);
    }

    // block reduction: 4-level xor within 16-lane groups, 9 channels
    const int lane = threadIdx.x & 63;
    const int wid  = threadIdx.x >> 6;
    float st9[9] = {s0, s1, s2, s3,
                    s4v.x + s4v.y, s5v.x + s5v.y,
                    s6v.x + s6v.y, s7v.x + s7v.y, s8v.x + s8v.y};
#pragma unroll
    for (int c = 0; c < 9; ++c) {
        float v = st9[c];
        v += __shfl_xor(v, 8);
        v += __shfl_xor(v, 4);
        v += __shfl_xor(v, 2);
        v += __shfl_xor(v, 1);
        st9[c] = v;
    }
    if ((lane & 15) == 0) {
        int gi = wid * 4 + (lane >> 4);
#pragma unroll
        for (int c = 0; c < 9; ++c) sred[gi][c] = st9[c];
    }
    __syncthreads();
    if (threadIdx.x < 9) {
        int c = threadIdx.x;
        float t = 0.0f;
#pragma unroll
        for (int gi = 0; gi < 16; ++gi) t += sred[gi][c];
        pr[c * 1024 + blockIdx.x] = t;
    }
}

// ---------------------------------------------------------------------------
// Kernel 2 (round 14): MFMA separable conv + SSIM, reading u8 quant directly.
//   No stage A: A-fragments are 8-byte global reads (L2/L3-resident qbuf),
//   unpacked in-register. LDS = HT[4][32][80] + Tg only. 2 data barriers.
//   4-channel algebra (r6): mu1, mu2, (p^2+t^2)/4, p*t.
// ---------------------------------------------------------------------------
__global__ __launch_bounds__(256, 6) void amsr2_conv(
        const unsigned char* __restrict__ qbuf, float* __restrict__ pr, GaussW gw)
{
    __shared__ alignas(16) _Float16 HT[NCH * HT_A];   // 20480 B
    __shared__ alignas(16) _Float16 Tg[16 * 32];      // 1024 B
    __shared__ float sredS[16];

    const int b  = blockIdx.z;
    const int r0 = blockIdx.y * TH;
    const int c0 = blockIdx.x * TW;
    const bool interior = (blockIdx.y < 31) && (blockIdx.x < 63);
    const unsigned char* qb0 = qbuf + (size_t)(b * 2) * NPIX;

    if (threadIdx.x < 16) {
        int n = threadIdx.x;
#pragma unroll
        for (int i = 0; i < 16; ++i) ((unsigned*)Tg)[n * 16 + i] = 0u;
#pragma unroll
        for (int j = 0; j < 11; ++j) Tg[n * 32 + n + j] = (_Float16)gw.g[j];
    }

    const int lane = threadIdx.x & 63;
    const int wid  = threadIdx.x >> 6;
    const int q    = lane >> 4;
    const int ml   = lane & 15;
    const f32x4 zero4 = {0.f, 0.f, 0.f, 0.f};
    const _Float16 hquart = (_Float16)0.25f;

    // preload this wave's A-fragments from global (u8, 8 B per image per pos).
    // clamped addresses for edge tiles: garbage only feeds discarded outputs.
    const int npos = (wid < 2) ? 3 : 2;
    uint2 fp[3], ft[3];
#pragma unroll
    for (int i = 0; i < 3; ++i) {
        if (i < npos) {
            int pos = wid + i * 4;
            int rb = (pos >> 1) * 16;
            int cb = pos & 1;
            int gr = r0 + rb + ml;       if (gr > HDIM - 1) gr = HDIM - 1;
            int gc = c0 + cb * 16 + q * 8; if (gc > WDIM - 8) gc = WDIM - 8;
            size_t off = (size_t)gr * WDIM + gc;
            fp[i] = *(const uint2*)(qb0 + off);
            ft[i] = *(const uint2*)(qb0 + NPIX + off);
        }
    }
    __syncthreads();   // Tg visible

    const half8 gfrag = *(const half8*)&Tg[ml * 32 + q * 8];

    // stage H: horizontal conv via MFMA; transposed write HT[arr][col][row]
#pragma unroll
    for (int i = 0; i < 3; ++i) {
        if (i < npos) {
            int pos = wid + i * 4;
            int rb = (pos >> 1) * 16;
            int cb = pos & 1;
            const half8 ap = unpack_u8x8(fp[i].x, fp[i].y);
            const half8 at = unpack_u8x8(ft[i].x, ft[i].y);
            half8 m2 = (ap * hquart) * ap;
            m2 = (at * hquart) * at + m2;
            f32x4 d0 = __builtin_amdgcn_mfma_f32_16x16x32_f16(ap,      gfrag, zero4, 0, 0, 0);
            f32x4 d1 = __builtin_amdgcn_mfma_f32_16x16x32_f16(at,      gfrag, zero4, 0, 0, 0);
            f32x4 d2 = __builtin_amdgcn_mfma_f32_16x16x32_f16(m2,      gfrag, zero4, 0, 0, 0);
            f32x4 d3 = __builtin_amdgcn_mfma_f32_16x16x32_f16(ap * at, gfrag, zero4, 0, 0, 0);
            int hb = (cb * 16 + ml) * HT_R + rb + q * 4;
            *(uint2*)&HT[0 * HT_A + hb] = make_uint2(pk2(d0[0], d0[1]), pk2(d0[2], d0[3]));
            *(uint2*)&HT[1 * HT_A + hb] = make_uint2(pk2(d1[0], d1[1]), pk2(d1[2], d1[3]));
            *(uint2*)&HT[2 * HT_A + hb] = make_uint2(pk2(d2[0], d2[1]), pk2(d2[2], d2[3]));
            *(uint2*)&HT[3 * HT_A + hb] = make_uint2(pk2(d3[0], d3[1]), pk2(d3[2], d3[3]));
        }
    }
    __syncthreads();

    // stage V: vertical conv via MFMA + SSIM map
    float ssum = 0.0f;
    f32x2 ssv = {0.f, 0.f};
    const int th_ = min(TH, OUTW - r0);
    const int tw_ = min(TW, OUTW - c0);
    for (int vp = wid; vp < 8; vp += 4) {
        int rb2 = (vp >> 1) * 16;
        int cb2 = vp & 1;
        f32x4 acc[NCH];
#pragma unroll
        for (int arr = 0; arr < NCH; ++arr) {
            const half8 bf = *(const half8*)&HT[arr * HT_A +
                                               (cb2 * 16 + ml) * HT_R + rb2 + q * 8];
            acc[arr] = __builtin_amdgcn_mfma_f32_16x16x32_f16(gfrag, bf, zero4, 0, 0, 0);
        }
        if (interior) {
#pragma unroll
            for (int pp = 0; pp < 2; ++pp) {
                f32x2 mu1 = {acc[0][2*pp], acc[0][2*pp+1]};
                f32x2 mu2 = {acc[1][2*pp], acc[1][2*pp+1]};
                f32x2 h2  = {acc[2][2*pp], acc[2][2*pp+1]};
                f32x2 h12 = {acc[3][2*pp], acc[3][2*pp+1]};
                f32x2 mu12 = mu1 * mu2, mu1s = mu1 * mu1, mu2s = mu2 * mu2;
                f32x2 sg12 = h12 - mu12;
                f32x2 sgs  = 4.0f * h2 - mu1s - mu2s;
                f32x2 num = (2.0f * mu12 + C1F) * (2.0f * sg12 + C2F);
                f32x2 den = (mu1s + mu2s + C1F) * (sgs + C2F);
                f32x2 rp = { __builtin_amdgcn_rcpf(den.x),
                             __builtin_amdgcn_rcpf(den.y) };
                ssv += num * rp;
            }
        } else {
            int col = cb2 * 16 + ml;
#pragma unroll
            for (int reg = 0; reg < 4; ++reg) {
                int row = rb2 + q * 4 + reg;
                if (row < th_ && col < tw_) {
                    float mu1 = acc[0][reg], mu2 = acc[1][reg];
                    float h2  = acc[2][reg], h12 = acc[3][reg];
                    float mu1s = mu1 * mu1, mu2s = mu2 * mu2, mu12 = mu1 * mu2;
                    float sg12 = h12 - mu12;
                    float sgs  = 4.0f * h2 - mu1s - mu2s;
                    float num = (2.0f * mu12 + C1F) * (2.0f * sg12 + C2F);
                    float den = (mu1s + mu2s + C1F) * (sgs + C2F);
                    ssum += num * __builtin_amdgcn_rcpf(den);
                }
            }
        }
    }

    // ssim-only block reduction
    float v = ssum + ssv.x + ssv.y;
    v += __shfl_xor(v, 8);
    v += __shfl_xor(v, 4);
    v += __shfl_xor(v, 2);
    v += __shfl_xor(v, 1);
    if ((lane & 15) == 0) sredS[wid * 4 + (lane >> 4)] = v;
    __syncthreads();
    if (threadIdx.x == 0) {
        float t = 0.0f;
#pragma unroll
        for (int gi = 0; gi < 16; ++gi) t += sredS[gi];
        int bid2 = ((b * 32) + blockIdx.y) * 64 + blockIdx.x;
        pr[PR9 + bid2] = t;
    }
}

// ---------------------------------------------------------------------------
// Final (split path): 36 segs of 256 (9ch x 4b) + 4 segs of 2048 (ssim).
// seg[] layout matches the old combine: seg[c*4+b], ssim at seg[36+b].
// ---------------------------------------------------------------------------
__global__ __launch_bounds__(256) void amsr2_final2(
        const float* __restrict__ pr, float* __restrict__ out)
{
    __shared__ double seg[40];
    int wid = threadIdx.x >> 6, lane = threadIdx.x & 63;
    for (int sidx = wid; sidx < 40; sidx += 4) {
        double acc = 0.0;
        if (sidx < 36) {
            int c = sidx >> 2, bb = sidx & 3;
            const float* base = pr + c * 1024 + bb * 256;
            float4 v = *(const float4*)(base + lane * 4);
            acc = (double)v.x + (double)v.y + (double)v.z + (double)v.w;
        } else {
            int bb = sidx - 36;
            const float* base = pr + PR9 + bb * 2048;
#pragma unroll
            for (int it = 0; it < 8; ++it) {
                float4 v = *(const float4*)(base + (it * 64 + lane) * 4);
                acc += (double)v.x + (double)v.y + (double)v.z + (double)v.w;
            }
        }
        for (int off = 32; off > 0; off >>= 1) acc += __shfl_down(acc, off);
        if (lane == 0) seg[sidx] = acc;
    }
    __syncthreads();
    if (threadIdx.x != 0) return;
    const double n = (double)NPIX;
    double sum0 = 0, sum1 = 0, sum2 = 0, sum3 = 0;
    for (int b = 0; b < 4; ++b) {
        sum0 += seg[0*4+b]; sum1 += seg[1*4+b]; sum2 += seg[2*4+b]; sum3 += seg[3*4+b];
    }
    double l1   = sum0 / (4.0 * n);
    double grad = sum1 / (4.0 * 2047.0 * 2048.0) + sum2 / (4.0 * 2048.0 * 2047.0);
    double energy = 0.0, dist = 0.0, psnr_sum = 0.0, ssim_sum = 0.0;
    for (int b = 0; b < 4; ++b) {
        double Sp  = seg[4*4+b],  St  = seg[5*4+b];
        double Spp = seg[6*4+b],  Stt = seg[7*4+b];
        double Su8 = seg[8*4+b],  Sss = seg[36+b];
        double pm = Sp / n, tm = St / n;
        double dm = pm - tm; energy += dm * dm;
        double vp = (Spp - n * pm * pm) / (n - 1.0);
        double vt = (Stt - n * tm * tm) / (n - 1.0);
        double ps = sqrt(fmax(vp, 0.0)), ts = sqrt(fmax(vt, 0.0));
        double dd = ps - ts; dist += dd * dd;
        double mse = Su8 / n;
        double psnr = (mse == 0.0) ? 100.0 : 10.0 * log10(65025.0 / fmax(mse, 1e-12));
        psnr_sum += psnr;
        ssim_sum += Sss / ((double)OUTW * (double)OUTW);
    }
    energy *= 0.25; dist *= 0.25;
    double range_pen = sum3 / (4.0 * n);
    double phys = energy + 0.5 * dist + 0.1 * range_pen;
    double ssim_mean = fmin(fmax(ssim_sum * 0.25, 0.0), 1.0);
    double total = l1 + 0.15 * grad + 0.05 * phys + 0.1 * (1.0 - ssim_mean);
    out[0] = (float)total;
    out[1] = (float)(psnr_sum * 0.25);
    out[2] = (float)ssim_mean;
}

// ===========================================================================
// FALLBACK: round-6 fused kernel (used only if ws_size < WS_NEEDED).
// ===========================================================================
__global__ __launch_bounds__(256, 7) void amsr2_fused_fb(
        const float* __restrict__ pred, const float* __restrict__ targ,
        float* __restrict__ pr, GaussW gw)
{
    __shared__ alignas(16) _Float16 Ubuf[NCH * HT_A];
    __shared__ float sred[16][10];
    _Float16* Iq = Ubuf;
    _Float16* Tg = Ubuf + 2 * IQ_H;

    const int b  = blockIdx.z;
    const int r0 = blockIdx.y * TH;
    const int c0 = blockIdx.x * TW;
    const float* pb = pred + (size_t)b * NPIX;
    const float* tb = targ + (size_t)b * NPIX;
    const bool interior = (blockIdx.y < 31) && (blockIdx.x < 63);

    if (threadIdx.x < 16) {
        int n = threadIdx.x;
#pragma unroll
        for (int i = 0; i < 16; ++i) ((unsigned*)Tg)[n * 16 + i] = 0u;
#pragma unroll
        for (int j = 0; j < 11; ++j) Tg[n * 32 + n + j] = (_Float16)gw.g[j];
    }

    float s0 = 0.f, s1 = 0.f, s2 = 0.f, s3 = 0.f, ssum = 0.f;
    f32x2 s4v = {0,0}, s5v = {0,0}, s6v = {0,0}, s7v = {0,0}, s8v = {0,0}, ssv = {0,0};

    if (interior) {
#pragma unroll
        for (int i = 0; i < 2; ++i) {
            int item = threadIdx.x + i * 256;
            int r = item >> 3, d = item & 7;
            const float* prow = pb + (size_t)(r0 + r) * WDIM + (c0 + d * 4);
            const float* trow = tb + (size_t)(r0 + r) * WDIM + (c0 + d * 4);
            float4 a4 = *(const float4*)prow;
            float4 b4 = *(const float4*)trow;
            float4 ad = *(const float4*)(prow + WDIM);
            float4 bd = *(const float4*)(trow + WDIM);
            float p5 = prow[4], t5 = trow[4];
            f32x2 a01 = {a4.x, a4.y}, a23 = {a4.z, a4.w};
            f32x2 b01 = {b4.x, b4.y}, b23 = {b4.z, b4.w};
            f32x2 dd01 = a01 - b01, dd23 = a23 - b23;
            float dd4 = p5 - t5;
            f32x2 g01 = f32x2{ad.x, ad.y} - f32x2{bd.x, bd.y};
            f32x2 g23 = f32x2{ad.z, ad.w} - f32x2{bd.z, bd.w};
            s0 += fabsf(dd01.x); s0 += fabsf(dd01.y);
            s0 += fabsf(dd23.x); s0 += fabsf(dd23.y);
            s1 += fabsf(dd01.x - g01.x); s1 += fabsf(dd01.y - g01.y);
            s1 += fabsf(dd23.x - g23.x); s1 += fabsf(dd23.y - g23.y);
            s2 += fabsf(dd01.x - dd01.y); s2 += fabsf(dd01.y - dd23.x);
            s2 += fabsf(dd23.x - dd23.y); s2 += fabsf(dd23.y - dd4);
            s3 += fmaxf(fabsf(a4.x) - 1.0f, 0.0f);
            s3 += fmaxf(fabsf(a4.y) - 1.0f, 0.0f);
            s3 += fmaxf(fabsf(a4.z) - 1.0f, 0.0f);
            s3 += fmaxf(fabsf(a4.w) - 1.0f, 0.0f);
            s4v += a01; s4v += a23;
            s5v += b01; s5v += b23;
            s6v += a01 * a01; s6v += a23 * a23;
            s7v += b01 * b01; s7v += b23 * b23;
            f32x2 qp01 = quant2(a01), qp23 = quant2(a23);
            f32x2 qt01 = quant2(b01), qt23 = quant2(b23);
            f32x2 qd01 = qp01 - qt01, qd23 = qp23 - qt23;
            s8v += qd01 * qd01; s8v += qd23 * qd23;
            *(uint2*)&Iq[r * IQ_S + d * 4] =
                make_uint2(pk2(qp01.x, qp01.y), pk2(qp23.x, qp23.y));
            *(uint2*)&Iq[IQ_H + r * IQ_S + d * 4] =
                make_uint2(pk2(qt01.x, qt01.y), pk2(qt23.x, qt23.y));
        }
        {
            int h = threadIdx.x;
            int r = h >> 2, d = 8 + (h & 3);
            const float* prow = pb + (size_t)(r0 + r) * WDIM + (c0 + d * 4);
            const float* trow = tb + (size_t)(r0 + r) * WDIM + (c0 + d * 4);
            float4 a4 = *(const float4*)prow;
            float4 b4 = *(const float4*)trow;
            f32x2 qp01 = quant2(f32x2{a4.x, a4.y}), qp23 = quant2(f32x2{a4.z, a4.w});
            f32x2 qt01 = quant2(f32x2{b4.x, b4.y}), qt23 = quant2(f32x2{b4.z, b4.w});
            *(uint2*)&Iq[r * IQ_S + d * 4] =
                make_uint2(pk2(qp01.x, qp01.y), pk2(qp23.x, qp23.y));
            *(uint2*)&Iq[IQ_H + r * IQ_S + d * 4] =
                make_uint2(pk2(qt01.x, qt01.y), pk2(qt23.x, qt23.y));
        }
        if (threadIdx.x < 192) {
            int h = threadIdx.x;
            int rq = h / 12;
            int r = 64 + rq, d = h - rq * 12;
            const float* prow = pb + (size_t)(r0 + r) * WDIM + (c0 + d * 4);
            const float* trow = tb + (size_t)(r0 + r) * WDIM + (c0 + d * 4);
            float4 a4 = *(const float4*)prow;
            float4 b4 = *(const float4*)trow;
            f32x2 qp01 = quant2(f32x2{a4.x, a4.y}), qp23 = quant2(f32x2{a4.z, a4.w});
            f32x2 qt01 = quant2(f32x2{b4.x, b4.y}), qt23 = quant2(f32x2{b4.z, b4.w});
            *(uint2*)&Iq[r * IQ_S + d * 4] =
                make_uint2(pk2(qp01.x, qp01.y), pk2(qp23.x, qp23.y));
            *(uint2*)&Iq[IQ_H + r * IQ_S + d * 4] =
                make_uint2(pk2(qt01.x, qt01.y), pk2(qt23.x, qt23.y));
        }
    } else {
#pragma unroll
        for (int i = 0; i < 2; ++i) {
            int item = threadIdx.x + i * 256;
            int r = item >> 3, d = item & 7;
            int gr = r0 + r, gc = c0 + d * 4;
            const float* prow = pb + (size_t)gr * WDIM + gc;
            const float* trow = tb + (size_t)gr * WDIM + gc;
            float4 a4 = *(const float4*)prow;
            float4 b4 = *(const float4*)trow;
            bool down = gr < (HDIM - 1);
            bool hasR = (gc + 4) < WDIM;
            float4 z4 = make_float4(0.f, 0.f, 0.f, 0.f);
            float4 ad = down ? *(const float4*)(prow + WDIM) : z4;
            float4 bd = down ? *(const float4*)(trow + WDIM) : z4;
            float p5 = hasR ? prow[4] : 0.0f;
            float t5 = hasR ? trow[4] : 0.0f;
            float pv[4] = {a4.x, a4.y, a4.z, a4.w};
            float tv[4] = {b4.x, b4.y, b4.z, b4.w};
            float pd[4] = {ad.x, ad.y, ad.z, ad.w};
            float td[4] = {bd.x, bd.y, bd.z, bd.w};
            float qp[4], qt[4];
#pragma unroll
            for (int k = 0; k < 4; ++k) { qp[k] = quant_u8f(pv[k]); qt[k] = quant_u8f(tv[k]); }
#pragma unroll
            for (int k = 0; k < 4; ++k) {
                float av = pv[k], bv = tv[k];
                float dd = av - bv;
                s0 += fabsf(dd);
                s3 += fmaxf(fabsf(av) - 1.0f, 0.0f);
                s4v.x += av;  s5v.x += bv;
                s6v.x = fmaf(av, av, s6v.x);
                s7v.x = fmaf(bv, bv, s7v.x);
                if (down) s1 += fabsf(dd - (pd[k] - td[k]));
                float nr  = (k < 3) ? pv[k + 1] : p5;
                float nt2 = (k < 3) ? tv[k + 1] : t5;
                if (k < 3 || hasR) s2 += fabsf(dd - (nr - nt2));
                float qd = qp[k] - qt[k];
                s8v.x = fmaf(qd, qd, s8v.x);
            }
            *(uint2*)&Iq[r * IQ_S + d * 4] =
                make_uint2(pk2(qp[0], qp[1]), pk2(qp[2], qp[3]));
            *(uint2*)&Iq[IQ_H + r * IQ_S + d * 4] =
                make_uint2(pk2(qt[0], qt[1]), pk2(qt[2], qt[3]));
        }
#pragma unroll
        for (int ph = 0; ph < 2; ++ph) {
            int r, d;
            bool active = true;
            if (ph == 0) { int h = threadIdx.x; r = h >> 2; d = 8 + (h & 3); }
            else {
                int h = threadIdx.x;
                active = h < 192;
                int rq = h / 12;
                r = 64 + rq; d = h - rq * 12;
            }
            if (active) {
                int gr = r0 + r, gc = c0 + d * 4;
                bool rowok = gr < HDIM;
                const float* prow = pb + (size_t)gr * WDIM + gc;
                const float* trow = tb + (size_t)gr * WDIM + gc;
                float qp[4], qt[4];
                if (rowok && (gc + 3) < WDIM) {
                    float4 a4 = *(const float4*)prow;
                    float4 b4 = *(const float4*)trow;
                    qp[0]=quant_u8f(a4.x); qp[1]=quant_u8f(a4.y); qp[2]=quant_u8f(a4.z); qp[3]=quant_u8f(a4.w);
                    qt[0]=quant_u8f(b4.x); qt[1]=quant_u8f(b4.y); qt[2]=quant_u8f(b4.z); qt[3]=quant_u8f(b4.w);
                } else {
#pragma unroll
                    for (int k = 0; k < 4; ++k) {
                        bool ok = rowok && (gc + k) < WDIM;
                        qp[k] = ok ? quant_u8f(prow[k]) : 0.0f;
                        qt[k] = ok ? quant_u8f(trow[k]) : 0.0f;
                    }
                }
                *(uint2*)&Iq[r * IQ_S + d * 4] =
                    make_uint2(pk2(qp[0], qp[1]), pk2(qp[2], qp[3]));
                *(uint2*)&Iq[IQ_H + r * IQ_S + d * 4] =
                    make_uint2(pk2(qt[0], qt[1]), pk2(qt[2], qt[3]));
            }
        }
    }
    __syncthreads();

    const int lane = threadIdx.x & 63;
    const int wid  = threadIdx.x >> 6;
    const int q    = lane >> 4;
    const int ml   = lane & 15;
    const half8 gfrag = *(const half8*)&Tg[ml * 32 + q * 8];
    const f32x4 zero4 = {0.f, 0.f, 0.f, 0.f};
    const _Float16 hquart = (_Float16)0.25f;

    const int npos = (wid < 2) ? 3 : 2;
    half8 hap[3], hat[3];
#pragma unroll
    for (int i = 0; i < 3; ++i) {
        if (i < npos) {
            int pos = wid + i * 4;
            int rb = (pos >> 1) * 16;
            int cb = pos & 1;
            int base = (rb + ml) * IQ_S + cb * 16 + q * 8;
            hap[i] = *(const half8*)&Iq[base];
            hat[i] = *(const half8*)&Iq[IQ_H + base];
        }
    }
    __syncthreads();

#pragma unroll
    for (int i = 0; i < 3; ++i) {
        if (i < npos) {
            int pos = wid + i * 4;
            int rb = (pos >> 1) * 16;
            int cb = pos & 1;
            const half8 ap = hap[i];
            const half8 at = hat[i];
            half8 m2 = (ap * hquart) * ap;
            m2 = (at * hquart) * at + m2;
            f32x4 d0 = __builtin_amdgcn_mfma_f32_16x16x32_f16(ap,      gfrag, zero4, 0, 0, 0);
            f32x4 d1 = __builtin_amdgcn_mfma_f32_16x16x32_f16(at,      gfrag, zero4, 0, 0, 0);
            f32x4 d2 = __builtin_amdgcn_mfma_f32_16x16x32_f16(m2,      gfrag, zero4, 0, 0, 0);
            f32x4 d3 = __builtin_amdgcn_mfma_f32_16x16x32_f16(ap * at, gfrag, zero4, 0, 0, 0);
            int hb = (cb * 16 + ml) * HT_R + rb + q * 4;
            *(uint2*)&Ubuf[0 * HT_A + hb] = make_uint2(pk2(d0[0], d0[1]), pk2(d0[2], d0[3]));
            *(uint2*)&Ubuf[1 * HT_A + hb] = make_uint2(pk2(d1[0], d1[1]), pk2(d1[2], d1[3]));
            *(uint2*)&Ubuf[2 * HT_A + hb] = make_uint2(pk2(d2[0], d2[1]), pk2(d2[2], d2[3]));
            *(uint2*)&Ubuf[3 * HT_A + hb] = make_uint2(pk2(d3[0], d3[1]), pk2(d3[2], d3[3]));
        }
    }
    __syncthreads();

    const int th_ = min(TH, OUTW - r0);
    const int tw_ = min(TW, OUTW - c0);
    for (int vp = wid; vp < 8; vp += 4) {
        int rb2 = (vp >> 1) * 16;
        int cb2 = vp & 1;
        f32x4 acc[NCH];
#pragma unroll
        for (int arr = 0; arr < NCH; ++arr) {
            const half8 bf = *(const half8*)&Ubuf[arr * HT_A +
                                                  (cb2 * 16 + ml) * HT_R + rb2 + q * 8];
            acc[arr] = __builtin_amdgcn_mfma_f32_16x16x32_f16(gfrag, bf, zero4, 0, 0, 0);
        }
        if (interior) {
#pragma unroll
            for (int pp = 0; pp < 2; ++pp) {
                f32x2 mu1 = {acc[0][2*pp], acc[0][2*pp+1]};
                f32x2 mu2 = {acc[1][2*pp], acc[1][2*pp+1]};
                f32x2 h2  = {acc[2][2*pp], acc[2][2*pp+1]};
                f32x2 h12 = {acc[3][2*pp], acc[3][2*pp+1]};
                f32x2 mu12 = mu1 * mu2, mu1s = mu1 * mu1, mu2s = mu2 * mu2;
                f32x2 sg12 = h12 - mu12;
                f32x2 sgs  = 4.0f * h2 - mu1s - mu2s;
                f32x2 num = (2.0f * mu12 + C1F) * (2.0f * sg12 + C2F);
                f32x2 den = (mu1s + mu2s + C1F) * (sgs + C2F);
                f32x2 rp = { __builtin_amdgcn_rcpf(den.x),
                             __builtin_amdgcn_rcpf(den.y) };
                ssv += num * rp;
            }
        } else {
            int col = cb2 * 16 + ml;
#pragma unroll
            for (int reg = 0; reg < 4; ++reg) {
                int row = rb2 + q * 4 + reg;
                if (row < th_ && col < tw_) {
                    float mu1 = acc[0][reg], mu2 = acc[1][reg];
                    float h2  = acc[2][reg], h12 = acc[3][reg];
                    float mu1s = mu1 * mu1, mu2s = mu2 * mu2, mu12 = mu1 * mu2;
                    float sg12 = h12 - mu12;
                    float sgs  = 4.0f * h2 - mu1s - mu2s;
                    float num = (2.0f * mu12 + C1F) * (2.0f * sg12 + C2F);
                    float den = (mu1s + mu2s + C1F) * (sgs + C2F);
                    ssum += num * __builtin_amdgcn_rcpf(den);
                }
            }
        }
    }

    float st10[10];
    st10[0] = s0; st10[1] = s1; st10[2] = s2; st10[3] = s3;
    st10[4] = s4v.x + s4v.y; st10[5] = s5v.x + s5v.y;
    st10[6] = s6v.x + s6v.y; st10[7] = s7v.x + s7v.y;
    st10[8] = s8v.x + s8v.y; st10[9] = ssum + ssv.x + ssv.y;
#pragma unroll
    for (int c = 0; c < 10; ++c) {
        float v = st10[c];
        v += __shfl_xor(v, 8);
        v += __shfl_xor(v, 4);
        v += __shfl_xor(v, 2);
        v += __shfl_xor(v, 1);
        st10[c] = v;
    }
    if ((lane & 15) == 0) {
        int g = wid * 4 + (lane >> 4);
#pragma unroll
        for (int c = 0; c < 10; ++c) sred[g][c] = st10[c];
    }
    __syncthreads();
    if (threadIdx.x < 10) {
        int c = threadIdx.x;
        float t = 0.0f;
#pragma unroll
        for (int g = 0; g < 16; ++g) t += sred[g][c];
        int bid = ((b * 32) + blockIdx.y) * 64 + blockIdx.x;
        pr[c * NBLK + bid] = t;
    }
}

__global__ __launch_bounds__(256) void amsr2_final_fb(
        const float* __restrict__ pr, float* __restrict__ out)
{
    __shared__ double seg[40];
    int wid = threadIdx.x >> 6, lane = threadIdx.x & 63;
    for (int sidx = wid; sidx < 40; sidx += 4) {
        int c = sidx >> 2, b = sidx & 3;
        const float* base = pr + c * NBLK + b * 2048;
        float4 v[8];
#pragma unroll
        for (int it = 0; it < 8; ++it)
            v[it] = *(const float4*)(base + (it * 64 + lane) * 4);
        double acc = 0.0;
#pragma unroll
        for (int it = 0; it < 8; ++it)
            acc += (double)v[it].x + (double)v[it].y + (double)v[it].z + (double)v[it].w;
        for (int off = 32; off > 0; off >>= 1) acc += __shfl_down(acc, off);
        if (lane == 0) seg[sidx] = acc;
    }
    __syncthreads();
    if (threadIdx.x != 0) return;
    const double n = (double)NPIX;
    double sum0 = 0, sum1 = 0, sum2 = 0, sum3 = 0;
    for (int b = 0; b < 4; ++b) {
        sum0 += seg[0*4+b]; sum1 += seg[1*4+b]; sum2 += seg[2*4+b]; sum3 += seg[3*4+b];
    }
    double l1   = sum0 / (4.0 * n);
    double grad = sum1 / (4.0 * 2047.0 * 2048.0) + sum2 / (4.0 * 2048.0 * 2047.0);
    double energy = 0.0, dist = 0.0, psnr_sum = 0.0, ssim_sum = 0.0;
    for (int b = 0; b < 4; ++b) {
        double Sp  = seg[4*4+b],  St  = seg[5*4+b];
        double Spp = seg[6*4+b],  Stt = seg[7*4+b];
        double Su8 = seg[8*4+b],  Sss = seg[9*4+b];
        double pm = Sp / n, tm = St / n;
        double dm = pm - tm; energy += dm * dm;
        double vp = (Spp - n * pm * pm) / (n - 1.0);
        double vt = (Stt - n * tm * tm) / (n - 1.0);
        double ps = sqrt(fmax(vp, 0.0)), ts = sqrt(fmax(vt, 0.0));
        double dd = ps - ts; dist += dd * dd;
        double mse = Su8 / n;
        double psnr = (mse == 0.0) ? 100.0 : 10.0 * log10(65025.0 / fmax(mse, 1e-12));
        psnr_sum += psnr;
        ssim_sum += Sss / ((double)OUTW * (double)OUTW);
    }
    energy *= 0.25; dist *= 0.25;
    double range_pen = sum3 / (4.0 * n);
    double phys = energy + 0.5 * dist + 0.1 * range_pen;
    double ssim_mean = fmin(fmax(ssim_sum * 0.25, 0.0), 1.0);
    double total = l1 + 0.15 * grad + 0.05 * phys + 0.1 * (1.0 - ssim_mean);
    out[0] = (float)total;
    out[1] = (float)(psnr_sum * 0.25);
    out[2] = (float)ssim_mean;
}

extern "C" void kernel_launch(void* const* d_in, const int* in_sizes, int n_in,
                              void* d_out, int out_size, void* d_ws, size_t ws_size,
                              hipStream_t stream)
{
    (void)in_sizes; (void)n_in; (void)out_size;
    const float* pred = (const float*)d_in[0];
    const float* targ = (const float*)d_in[1];
    float* out = (float*)d_out;

    GaussW gw;                            // host-side f64 Gaussian, cast to f32
    {
        double e[11], sm = 0.0;
        for (int i = 0; i < 11; ++i) {
            double d = (double)(i - 5);
            e[i] = exp(-(d * d) / 4.5);
            sm += e[i];
        }
        for (int i = 0; i < 11; ++i) gw.g[i] = (float)(e[i] / sm);
    }

    if (ws_size >= WS_NEEDED) {
        unsigned char* qbuf = (unsigned char*)d_ws;
        float* pr = (float*)((char*)d_ws + QBYTES);
        amsr2_stream<<<dim3(1024, 1, 1), 256, 0, stream>>>(pred, targ, qbuf, pr);
        amsr2_conv<<<dim3(64, 32, 4), 256, 0, stream>>>(qbuf, pr, gw);
        amsr2_final2<<<1, 256, 0, stream>>>(pr, out);
    } else {
        float* pr = (float*)d_ws;
        amsr2_fused_fb<<<dim3(64, 32, 4), 256, 0, stream>>>(pred, targ, pr, gw);
        amsr2_final_fb<<<1, 256, 0, stream>>>(pr, out);
    }
}

// Round 8
// 175.034 us; speedup vs baseline: 1.1598x; 1.1598x over previous
//
#include <hip/hip_runtime.h>
#include <math.h>

#define HDIM 2048
#define WDIM 2048
#define NPIX (HDIM*WDIM)
#define OUTW 2038          /* valid conv output size: 2048-10 */

#define C1F 6.5025f        /* (0.01*255)^2 */
#define C2F 58.5225f       /* (0.03*255)^2 */

constexpr int TH   = 64, TW = 32;  // output tile
constexpr int IN_R = 80;           // input rows staged (5 MFMA row-blocks of 16)
constexpr int IQ_S = 56;           // f16 staging row stride (112 B)
constexpr int IQ_H = IN_R * IQ_S;  // 4480 f16 per image
constexpr int HT_R = 80;           // HT row stride: [arr][col][row]
constexpr int HT_A = 32 * HT_R;    // 2560 f16 per array
constexpr int NCH  = 4;            // mu1, mu2, (p^2+t^2)/4, p*t
constexpr int NBLK = 8192;         // 64 x 32 x 4 blocks

struct GaussW { float g[11]; };

typedef _Float16 half8 __attribute__((ext_vector_type(8)));
typedef float    f32x4 __attribute__((ext_vector_type(4)));
typedef float    f32x2 __attribute__((ext_vector_type(2)));

// quant: bit-exact vs reference sequence. (clip(x)+1)*0.5 then *255 ==
// (clip(x)+1)*127.5; trunc == floor for v >= 0. Must stay add-then-mul.
__device__ __forceinline__ float quant_u8f(float x) {
    float c = __builtin_amdgcn_fmed3f(x, -1.0f, 1.0f);
    return truncf((c + 1.0f) * 127.5f);
}
__device__ __forceinline__ f32x2 quant2(f32x2 x) {
    f32x2 c = { __builtin_amdgcn_fmed3f(x.x, -1.0f, 1.0f),
                __builtin_amdgcn_fmed3f(x.y, -1.0f, 1.0f) };
    f32x2 v = (c + 1.0f) * 127.5f;     // pk_add then pk_mul: matches reference
    return { truncf(v.x), truncf(v.y) };
}
__device__ __forceinline__ unsigned pk2(float a, float b) {
    return __builtin_bit_cast(unsigned, __builtin_amdgcn_cvt_pkrtz(a, b));
}

// ---------------------------------------------------------------------------
// Fused kernel (round 15: stage-A load batch pinned by sched_barrier).
//   Unifying evidence r0-r7: every variant runs at ~2.2-2.3 TB/s with no pipe
//   saturated, incl. a pure streaming kernel (r7: 13.5% VALU, 2.3 TB/s) ->
//   memory-LATENCY bound; compiler keeps VGPR=40 and serializes loads.
//   Fix: issue ALL 16 stage-A loads, then __builtin_amdgcn_sched_barrier(0)
//   (hard fence -- loads cannot be re-sunk past it; forces live ranges so the
//   allocator must buffer them). launch_bounds (256,4) -> 128-VGPR cap.
//   Base: r6 4-channel SSIM algebra, 21.5 KB LDS union.
// Channels: 0:l1 1:gxH 2:gyW 3:relu 4:sp 5:st 6:spp 7:stt 8:su8 9:ssim
// ---------------------------------------------------------------------------
__global__ __launch_bounds__(256, 4) void amsr2_fused(
        const float* __restrict__ pred, const float* __restrict__ targ,
        float* __restrict__ pr, GaussW gw)
{
    __shared__ alignas(16) _Float16 Ubuf[NCH * HT_A];   // 10240 f16 = 20480 B
    __shared__ float sred[16][10];
    _Float16* Iq = Ubuf;                     // [0, 17920 B): 2 x 80 x 56 f16
    _Float16* Tg = Ubuf + 2 * IQ_H;          // [17920, 18944 B): 16 x 32 f16

    const int b  = blockIdx.z;
    const int r0 = blockIdx.y * TH;
    const int c0 = blockIdx.x * TW;
    const float* pb = pred + (size_t)b * NPIX;
    const float* tb = targ + (size_t)b * NPIX;
    const bool interior = (blockIdx.y < 31) && (blockIdx.x < 63);

    // ---- banded Gaussian table (threads 0..15; each owns its row) ----
    if (threadIdx.x < 16) {
        int n = threadIdx.x;
#pragma unroll
        for (int i = 0; i < 16; ++i) ((unsigned*)Tg)[n * 16 + i] = 0u;
#pragma unroll
        for (int j = 0; j < 11; ++j) Tg[n * 32 + n + j] = (_Float16)gw.g[j];
    }

    float s0 = 0.f, s1 = 0.f, s2 = 0.f, s3 = 0.f, ssum = 0.f;
    f32x2 s4v = {0,0}, s5v = {0,0}, s6v = {0,0}, s7v = {0,0}, s8v = {0,0}, ssv = {0,0};

    // ---- stage A: 80 rows x 48 cols staged; core(512) + halo(256+192) ----
    if (interior) {
        // ======== load-issue phase: 16 loads batched, then hard fence ========
        float4 cA[2], cB[2], cAD[2], cBD[2];
        float cp5[2], ct5[2];
#pragma unroll
        for (int i = 0; i < 2; ++i) {
            int item = threadIdx.x + i * 256;
            int r = item >> 3, d = item & 7;
            const float* prow = pb + (size_t)(r0 + r) * WDIM + (c0 + d * 4);
            const float* trow = tb + (size_t)(r0 + r) * WDIM + (c0 + d * 4);
            cA[i]  = *(const float4*)prow;
            cB[i]  = *(const float4*)trow;
            cAD[i] = *(const float4*)(prow + WDIM);
            cBD[i] = *(const float4*)(trow + WDIM);
            cp5[i] = prow[4];
            ct5[i] = trow[4];
        }
        float4 h0A, h0B;
        const int h0r = threadIdx.x >> 2, h0d = 8 + (threadIdx.x & 3);
        {
            const float* prow = pb + (size_t)(r0 + h0r) * WDIM + (c0 + h0d * 4);
            const float* trow = tb + (size_t)(r0 + h0r) * WDIM + (c0 + h0d * 4);
            h0A = *(const float4*)prow;
            h0B = *(const float4*)trow;
        }
        float4 h1A = make_float4(0.f, 0.f, 0.f, 0.f);
        float4 h1B = h1A;
        const bool act1 = threadIdx.x < 192;
        const int rq1 = threadIdx.x / 12;
        const int h1r = 64 + rq1, h1d = threadIdx.x - rq1 * 12;
        if (act1) {
            const float* prow = pb + (size_t)(r0 + h1r) * WDIM + (c0 + h1d * 4);
            const float* trow = tb + (size_t)(r0 + h1r) * WDIM + (c0 + h1d * 4);
            h1A = *(const float4*)prow;
            h1B = *(const float4*)trow;
        }
        // hard scheduling fence: nothing crosses; loads stay batched above
        __builtin_amdgcn_sched_barrier(0);

        // ======== compute phase (consumes the buffered loads) ========
#pragma unroll
        for (int i = 0; i < 2; ++i) {
            int item = threadIdx.x + i * 256;
            int r = item >> 3, d = item & 7;
            float4 a4 = cA[i], b4 = cB[i], ad = cAD[i], bd = cBD[i];
            float p5 = cp5[i], t5 = ct5[i];

            f32x2 a01 = {a4.x, a4.y}, a23 = {a4.z, a4.w};
            f32x2 b01 = {b4.x, b4.y}, b23 = {b4.z, b4.w};
            f32x2 dd01 = a01 - b01, dd23 = a23 - b23;
            float dd4 = p5 - t5;
            f32x2 g01 = f32x2{ad.x, ad.y} - f32x2{bd.x, bd.y};
            f32x2 g23 = f32x2{ad.z, ad.w} - f32x2{bd.z, bd.w};

            s0 += fabsf(dd01.x); s0 += fabsf(dd01.y);
            s0 += fabsf(dd23.x); s0 += fabsf(dd23.y);
            s1 += fabsf(dd01.x - g01.x); s1 += fabsf(dd01.y - g01.y);
            s1 += fabsf(dd23.x - g23.x); s1 += fabsf(dd23.y - g23.y);
            s2 += fabsf(dd01.x - dd01.y); s2 += fabsf(dd01.y - dd23.x);
            s2 += fabsf(dd23.x - dd23.y); s2 += fabsf(dd23.y - dd4);
            s3 += fmaxf(fabsf(a4.x) - 1.0f, 0.0f);
            s3 += fmaxf(fabsf(a4.y) - 1.0f, 0.0f);
            s3 += fmaxf(fabsf(a4.z) - 1.0f, 0.0f);
            s3 += fmaxf(fabsf(a4.w) - 1.0f, 0.0f);
            s4v += a01; s4v += a23;
            s5v += b01; s5v += b23;
            s6v += a01 * a01; s6v += a23 * a23;
            s7v += b01 * b01; s7v += b23 * b23;
            f32x2 qp01 = quant2(a01), qp23 = quant2(a23);
            f32x2 qt01 = quant2(b01), qt23 = quant2(b23);
            f32x2 qd01 = qp01 - qt01, qd23 = qp23 - qt23;
            s8v += qd01 * qd01; s8v += qd23 * qd23;

            *(uint2*)&Iq[r * IQ_S + d * 4] =
                make_uint2(pk2(qp01.x, qp01.y), pk2(qp23.x, qp23.y));
            *(uint2*)&Iq[IQ_H + r * IQ_S + d * 4] =
                make_uint2(pk2(qt01.x, qt01.y), pk2(qt23.x, qt23.y));
        }
        // halo 0: rows 0..63, cols 32..47
        {
            f32x2 qp01 = quant2(f32x2{h0A.x, h0A.y}), qp23 = quant2(f32x2{h0A.z, h0A.w});
            f32x2 qt01 = quant2(f32x2{h0B.x, h0B.y}), qt23 = quant2(f32x2{h0B.z, h0B.w});
            *(uint2*)&Iq[h0r * IQ_S + h0d * 4] =
                make_uint2(pk2(qp01.x, qp01.y), pk2(qp23.x, qp23.y));
            *(uint2*)&Iq[IQ_H + h0r * IQ_S + h0d * 4] =
                make_uint2(pk2(qt01.x, qt01.y), pk2(qt23.x, qt23.y));
        }
        // halo 1: rows 64..79, all 12 dword-groups (192 items)
        if (act1) {
            f32x2 qp01 = quant2(f32x2{h1A.x, h1A.y}), qp23 = quant2(f32x2{h1A.z, h1A.w});
            f32x2 qt01 = quant2(f32x2{h1B.x, h1B.y}), qt23 = quant2(f32x2{h1B.z, h1B.w});
            *(uint2*)&Iq[h1r * IQ_S + h1d * 4] =
                make_uint2(pk2(qp01.x, qp01.y), pk2(qp23.x, qp23.y));
            *(uint2*)&Iq[IQ_H + h1r * IQ_S + h1d * 4] =
                make_uint2(pk2(qt01.x, qt01.y), pk2(qt23.x, qt23.y));
        }
    } else {
        // edge tiles (~4.6% of blocks): guarded path, unchanged
#pragma unroll
        for (int i = 0; i < 2; ++i) {
            int item = threadIdx.x + i * 256;
            int r = item >> 3, d = item & 7;
            int gr = r0 + r, gc = c0 + d * 4;
            const float* prow = pb + (size_t)gr * WDIM + gc;
            const float* trow = tb + (size_t)gr * WDIM + gc;
            float4 a4 = *(const float4*)prow;
            float4 b4 = *(const float4*)trow;
            bool down = gr < (HDIM - 1);
            bool hasR = (gc + 4) < WDIM;
            float4 z4 = make_float4(0.f, 0.f, 0.f, 0.f);
            float4 ad = down ? *(const float4*)(prow + WDIM) : z4;
            float4 bd = down ? *(const float4*)(trow + WDIM) : z4;
            float p5 = hasR ? prow[4] : 0.0f;
            float t5 = hasR ? trow[4] : 0.0f;
            float pv[4] = {a4.x, a4.y, a4.z, a4.w};
            float tv[4] = {b4.x, b4.y, b4.z, b4.w};
            float pd[4] = {ad.x, ad.y, ad.z, ad.w};
            float td[4] = {bd.x, bd.y, bd.z, bd.w};
            float qp[4], qt[4];
#pragma unroll
            for (int k = 0; k < 4; ++k) { qp[k] = quant_u8f(pv[k]); qt[k] = quant_u8f(tv[k]); }
#pragma unroll
            for (int k = 0; k < 4; ++k) {
                float av = pv[k], bv = tv[k];
                float dd = av - bv;
                s0 += fabsf(dd);
                s3 += fmaxf(fabsf(av) - 1.0f, 0.0f);
                s4v.x += av;  s5v.x += bv;
                s6v.x = fmaf(av, av, s6v.x);
                s7v.x = fmaf(bv, bv, s7v.x);
                if (down) s1 += fabsf(dd - (pd[k] - td[k]));
                float nr  = (k < 3) ? pv[k + 1] : p5;
                float nt2 = (k < 3) ? tv[k + 1] : t5;
                if (k < 3 || hasR) s2 += fabsf(dd - (nr - nt2));
                float qd = qp[k] - qt[k];
                s8v.x = fmaf(qd, qd, s8v.x);
            }
            *(uint2*)&Iq[r * IQ_S + d * 4] =
                make_uint2(pk2(qp[0], qp[1]), pk2(qp[2], qp[3]));
            *(uint2*)&Iq[IQ_H + r * IQ_S + d * 4] =
                make_uint2(pk2(qt[0], qt[1]), pk2(qt[2], qt[3]));
        }
#pragma unroll
        for (int ph = 0; ph < 2; ++ph) {
            int r, d;
            bool active = true;
            if (ph == 0) { int h = threadIdx.x; r = h >> 2; d = 8 + (h & 3); }
            else {
                int h = threadIdx.x;
                active = h < 192;
                int rq = h / 12;
                r = 64 + rq; d = h - rq * 12;
            }
            if (active) {
                int gr = r0 + r, gc = c0 + d * 4;
                bool rowok = gr < HDIM;
                const float* prow = pb + (size_t)gr * WDIM + gc;
                const float* trow = tb + (size_t)gr * WDIM + gc;
                float qp[4], qt[4];
                if (rowok && (gc + 3) < WDIM) {
                    float4 a4 = *(const float4*)prow;
                    float4 b4 = *(const float4*)trow;
                    qp[0]=quant_u8f(a4.x); qp[1]=quant_u8f(a4.y); qp[2]=quant_u8f(a4.z); qp[3]=quant_u8f(a4.w);
                    qt[0]=quant_u8f(b4.x); qt[1]=quant_u8f(b4.y); qt[2]=quant_u8f(b4.z); qt[3]=quant_u8f(b4.w);
                } else {
#pragma unroll
                    for (int k = 0; k < 4; ++k) {
                        bool ok = rowok && (gc + k) < WDIM;
                        qp[k] = ok ? quant_u8f(prow[k]) : 0.0f;
                        qt[k] = ok ? quant_u8f(trow[k]) : 0.0f;
                    }
                }
                *(uint2*)&Iq[r * IQ_S + d * 4] =
                    make_uint2(pk2(qp[0], qp[1]), pk2(qp[2], qp[3]));
                *(uint2*)&Iq[IQ_H + r * IQ_S + d * 4] =
                    make_uint2(pk2(qt[0], qt[1]), pk2(qt[2], qt[3]));
            }
        }
    }
    __syncthreads();

    const int lane = threadIdx.x & 63;
    const int wid  = threadIdx.x >> 6;
    const int q    = lane >> 4;
    const int ml   = lane & 15;
    // shared Gaussian fragment: horizontal B-operand == vertical A-operand.
    // Loaded BEFORE the aliasing barrier -- Tg is dead after this.
    const half8 gfrag = *(const half8*)&Tg[ml * 32 + q * 8];
    const f32x4 zero4 = {0.f, 0.f, 0.f, 0.f};
    const _Float16 hquart = (_Float16)0.25f;

    // ---- stage H part 1: preload A-fragments for this wave's positions ----
    const int npos = (wid < 2) ? 3 : 2;
    half8 hap[3], hat[3];
#pragma unroll
    for (int i = 0; i < 3; ++i) {
        if (i < npos) {
            int pos = wid + i * 4;
            int rb = (pos >> 1) * 16;
            int cb = pos & 1;
            int base = (rb + ml) * IQ_S + cb * 16 + q * 8;
            hap[i] = *(const half8*)&Iq[base];
            hat[i] = *(const half8*)&Iq[IQ_H + base];
        }
    }
    __syncthreads();   // all Iq/Tg reads done -> HT may overwrite the union buffer

    // ---- stage H part 2: horizontal conv via MFMA; HT aliases Iq+Tg ----
#pragma unroll
    for (int i = 0; i < 3; ++i) {
        if (i < npos) {
            int pos = wid + i * 4;
            int rb = (pos >> 1) * 16;
            int cb = pos & 1;
            const half8 ap = hap[i];
            const half8 at = hat[i];
            half8 m2 = (ap * hquart) * ap;
            m2 = (at * hquart) * at + m2;
            f32x4 d0 = __builtin_amdgcn_mfma_f32_16x16x32_f16(ap,      gfrag, zero4, 0, 0, 0);
            f32x4 d1 = __builtin_amdgcn_mfma_f32_16x16x32_f16(at,      gfrag, zero4, 0, 0, 0);
            f32x4 d2 = __builtin_amdgcn_mfma_f32_16x16x32_f16(m2,      gfrag, zero4, 0, 0, 0);
            f32x4 d3 = __builtin_amdgcn_mfma_f32_16x16x32_f16(ap * at, gfrag, zero4, 0, 0, 0);
            int hb = (cb * 16 + ml) * HT_R + rb + q * 4;
            *(uint2*)&Ubuf[0 * HT_A + hb] = make_uint2(pk2(d0[0], d0[1]), pk2(d0[2], d0[3]));
            *(uint2*)&Ubuf[1 * HT_A + hb] = make_uint2(pk2(d1[0], d1[1]), pk2(d1[2], d1[3]));
            *(uint2*)&Ubuf[2 * HT_A + hb] = make_uint2(pk2(d2[0], d2[1]), pk2(d2[2], d2[3]));
            *(uint2*)&Ubuf[3 * HT_A + hb] = make_uint2(pk2(d3[0], d3[1]), pk2(d3[2], d3[3]));
        }
    }
    __syncthreads();

    // ---- stage V: vertical conv via MFMA + SSIM map; 8 positions, 2/wave ----
    const int th_ = min(TH, OUTW - r0);
    const int tw_ = min(TW, OUTW - c0);
    for (int vp = wid; vp < 8; vp += 4) {
        int rb2 = (vp >> 1) * 16;
        int cb2 = vp & 1;
        f32x4 acc[NCH];
#pragma unroll
        for (int arr = 0; arr < NCH; ++arr) {
            const half8 bf = *(const half8*)&Ubuf[arr * HT_A +
                                                  (cb2 * 16 + ml) * HT_R + rb2 + q * 8];
            acc[arr] = __builtin_amdgcn_mfma_f32_16x16x32_f16(gfrag, bf, zero4, 0, 0, 0);
        }
        if (interior) {
#pragma unroll
            for (int pp = 0; pp < 2; ++pp) {
                f32x2 mu1 = {acc[0][2*pp], acc[0][2*pp+1]};
                f32x2 mu2 = {acc[1][2*pp], acc[1][2*pp+1]};
                f32x2 h2  = {acc[2][2*pp], acc[2][2*pp+1]};
                f32x2 h12 = {acc[3][2*pp], acc[3][2*pp+1]};
                f32x2 mu12 = mu1 * mu2, mu1s = mu1 * mu1, mu2s = mu2 * mu2;
                f32x2 sg12 = h12 - mu12;
                f32x2 sgs  = 4.0f * h2 - mu1s - mu2s;
                f32x2 num = (2.0f * mu12 + C1F) * (2.0f * sg12 + C2F);
                f32x2 den = (mu1s + mu2s + C1F) * (sgs + C2F);
                f32x2 rp = { __builtin_amdgcn_rcpf(den.x),
                             __builtin_amdgcn_rcpf(den.y) };
                ssv += num * rp;
            }
        } else {
            int col = cb2 * 16 + ml;
#pragma unroll
            for (int reg = 0; reg < 4; ++reg) {
                int row = rb2 + q * 4 + reg;
                if (row < th_ && col < tw_) {
                    float mu1 = acc[0][reg], mu2 = acc[1][reg];
                    float h2  = acc[2][reg], h12 = acc[3][reg];
                    float mu1s = mu1 * mu1, mu2s = mu2 * mu2, mu12 = mu1 * mu2;
                    float sg12 = h12 - mu12;
                    float sgs  = 4.0f * h2 - mu1s - mu2s;
                    float num = (2.0f * mu12 + C1F) * (2.0f * sg12 + C2F);
                    float den = (mu1s + mu2s + C1F) * (sgs + C2F);
                    ssum += num * __builtin_amdgcn_rcpf(den);
                }
            }
        }
    }

    // ---- block reduction: 4-level xor tree within 16-lane groups ----
    float st10[10];
    st10[0] = s0; st10[1] = s1; st10[2] = s2; st10[3] = s3;
    st10[4] = s4v.x + s4v.y; st10[5] = s5v.x + s5v.y;
    st10[6] = s6v.x + s6v.y; st10[7] = s7v.x + s7v.y;
    st10[8] = s8v.x + s8v.y; st10[9] = ssum + ssv.x + ssv.y;
#pragma unroll
    for (int c = 0; c < 10; ++c) {
        float v = st10[c];
        v += __shfl_xor(v, 8);
        v += __shfl_xor(v, 4);
        v += __shfl_xor(v, 2);
        v += __shfl_xor(v, 1);
        st10[c] = v;
    }
    if ((lane & 15) == 0) {
        int g = wid * 4 + (lane >> 4);
#pragma unroll
        for (int c = 0; c < 10; ++c) sred[g][c] = st10[c];
    }
    __syncthreads();
    if (threadIdx.x < 10) {
        int c = threadIdx.x;
        float t = 0.0f;
#pragma unroll
        for (int g = 0; g < 16; ++g) t += sred[g][c];
        int bid = ((b * 32) + blockIdx.y) * 64 + blockIdx.x;
        pr[c * NBLK + bid] = t;
    }
}

// ---------------------------------------------------------------------------
// Final: ONE block. 40 segments of 2048 contiguous floats, coalesced float4
// reads, f64 shfl-reduce; thread 0 does the scalar combine.
// ---------------------------------------------------------------------------
__global__ __launch_bounds__(256) void amsr2_final(
        const float* __restrict__ pr, float* __restrict__ out)
{
    __shared__ double seg[40];
    int wid = threadIdx.x >> 6, lane = threadIdx.x & 63;
    for (int sidx = wid; sidx < 40; sidx += 4) {
        int c = sidx >> 2, b = sidx & 3;
        const float* base = pr + c * NBLK + b * 2048;
        float4 v[8];
#pragma unroll
        for (int it = 0; it < 8; ++it)
            v[it] = *(const float4*)(base + (it * 64 + lane) * 4);
        double acc = 0.0;
#pragma unroll
        for (int it = 0; it < 8; ++it)
            acc += (double)v[it].x + (double)v[it].y + (double)v[it].z + (double)v[it].w;
        for (int off = 32; off > 0; off >>= 1) acc += __shfl_down(acc, off);
        if (lane == 0) seg[sidx] = acc;
    }
    __syncthreads();
    if (threadIdx.x != 0) return;
    const double n = (double)NPIX;
    double sum0 = 0, sum1 = 0, sum2 = 0, sum3 = 0;
    for (int b = 0; b < 4; ++b) {
        sum0 += seg[0*4+b]; sum1 += seg[1*4+b]; sum2 += seg[2*4+b]; sum3 += seg[3*4+b];
    }
    double l1   = sum0 / (4.0 * n);
    double grad = sum1 / (4.0 * 2047.0 * 2048.0) + sum2 / (4.0 * 2048.0 * 2047.0);
    double energy = 0.0, dist = 0.0, psnr_sum = 0.0, ssim_sum = 0.0;
    for (int b = 0; b < 4; ++b) {
        double Sp  = seg[4*4+b],  St  = seg[5*4+b];
        double Spp = seg[6*4+b],  Stt = seg[7*4+b];
        double Su8 = seg[8*4+b],  Sss = seg[9*4+b];
        double pm = Sp / n, tm = St / n;
        double dm = pm - tm; energy += dm * dm;
        double vp = (Spp - n * pm * pm) / (n - 1.0);
        double vt = (Stt - n * tm * tm) / (n - 1.0);
        double ps = sqrt(fmax(vp, 0.0)), ts = sqrt(fmax(vt, 0.0));
        double dd = ps - ts; dist += dd * dd;
        double mse = Su8 / n;
        double psnr = (mse == 0.0) ? 100.0 : 10.0 * log10(65025.0 / fmax(mse, 1e-12));
        psnr_sum += psnr;
        ssim_sum += Sss / ((double)OUTW * (double)OUTW);
    }
    energy *= 0.25; dist *= 0.25;
    double range_pen = sum3 / (4.0 * n);
    double phys = energy + 0.5 * dist + 0.1 * range_pen;
    double ssim_mean = fmin(fmax(ssim_sum * 0.25, 0.0), 1.0);
    double total = l1 + 0.15 * grad + 0.05 * phys + 0.1 * (1.0 - ssim_mean);
    out[0] = (float)total;
    out[1] = (float)(psnr_sum * 0.25);
    out[2] = (float)ssim_mean;
}

extern "C" void kernel_launch(void* const* d_in, const int* in_sizes, int n_in,
                              void* d_out, int out_size, void* d_ws, size_t ws_size,
                              hipStream_t stream)
{
    (void)in_sizes; (void)n_in; (void)out_size; (void)ws_size;
    const float* pred = (const float*)d_in[0];
    const float* targ = (const float*)d_in[1];
    float* out = (float*)d_out;
    float* pr  = (float*)d_ws;            // 10 * 8192 floats of per-block partials

    GaussW gw;                            // host-side f64 Gaussian, cast to f32
    {
        double e[11], sm = 0.0;
        for (int i = 0; i < 11; ++i) {
            double d = (double)(i - 5);
            e[i] = exp(-(d * d) / 4.5);
            sm += e[i];
        }
        for (int i = 0; i < 11; ++i) gw.g[i] = (float)(e[i] / sm);
    }

    amsr2_fused<<<dim3(64, 32, 4), 256, 0, stream>>>(pred, targ, pr, gw);
    amsr2_final<<<1, 256, 0, stream>>>(pr, out);
}

// Round 9
// 174.032 us; speedup vs baseline: 1.1664x; 1.0058x over previous
//
#include <hip/hip_runtime.h>
#include <math.h>

#define HDIM 2048
#define WDIM 2048
#define NPIX (HDIM*WDIM)
#define OUTW 2038          /* valid conv output size: 2048-10 */

#define C1F 6.5025f        /* (0.01*255)^2 */
#define C2F 58.5225f       /* (0.03*255)^2 */

constexpr int TH   = 64, TW = 32;  // output tile
constexpr int IN_R = 80;           // input rows staged (5 MFMA row-blocks of 16)
constexpr int IQ_S = 56;           // f16 staging row stride (112 B)
constexpr int IQ_H = IN_R * IQ_S;  // 4480 f16 per image
constexpr int HT_R = 80;           // HT row stride: [arr][col][row]
constexpr int HT_A = 32 * HT_R;    // 2560 f16 per array
constexpr int NCH  = 4;            // mu1, mu2, (p^2+t^2)/4, p*t
constexpr int NBLK = 8192;         // 64 x 32 x 4 blocks

struct GaussW { float g[11]; };

typedef _Float16 half8 __attribute__((ext_vector_type(8)));
typedef float    f32x4 __attribute__((ext_vector_type(4)));
typedef float    f32x2 __attribute__((ext_vector_type(2)));

// raw async global loads: invisible to the compiler's waitcnt insertion, so
// they stay batched; ONE s_waitcnt vmcnt(0) drains all 16. sched_barrier(0)
// after the waitcnt per guide rule #18 (consumers must not hoist above it).
#define GLOAD4(dst, ptr) \
    asm volatile("global_load_dwordx4 %0, %1, off" : "=v"(dst) : "v"(ptr))
#define GLOAD1(dst, ptr) \
    asm volatile("global_load_dword %0, %1, off" : "=v"(dst) : "v"(ptr))

// quant: bit-exact vs reference sequence. (clip(x)+1)*0.5 then *255 ==
// (clip(x)+1)*127.5; trunc == floor for v >= 0. Must stay add-then-mul.
__device__ __forceinline__ float quant_u8f(float x) {
    float c = __builtin_amdgcn_fmed3f(x, -1.0f, 1.0f);
    return truncf((c + 1.0f) * 127.5f);
}
__device__ __forceinline__ f32x2 quant2(f32x2 x) {
    f32x2 c = { __builtin_amdgcn_fmed3f(x.x, -1.0f, 1.0f),
                __builtin_amdgcn_fmed3f(x.y, -1.0f, 1.0f) };
    f32x2 v = (c + 1.0f) * 127.5f;     // pk_add then pk_mul: matches reference
    return { truncf(v.x), truncf(v.y) };
}
__device__ __forceinline__ unsigned pk2(float a, float b) {
    return __builtin_bit_cast(unsigned, __builtin_amdgcn_cvt_pkrtz(a, b));
}

// ---------------------------------------------------------------------------
// Fused kernel (round 16: inline-asm stage-A load batch).
//   r8 refuted compiler-cooperative batching (sched_barrier defeated, VGPR
//   stuck at 40). Escalation: asm volatile global_load -- the compiler cannot
//   see these as loads, so it cannot serialize them with per-load waitcnts.
//   16 loads in flight per thread, one vmcnt(0) drain, then compute.
//   Base: r6 4-channel SSIM algebra, 21.5 KB LDS union.
// Channels: 0:l1 1:gxH 2:gyW 3:relu 4:sp 5:st 6:spp 7:stt 8:su8 9:ssim
// ---------------------------------------------------------------------------
__global__ __launch_bounds__(256, 4) void amsr2_fused(
        const float* __restrict__ pred, const float* __restrict__ targ,
        float* __restrict__ pr, GaussW gw)
{
    __shared__ alignas(16) _Float16 Ubuf[NCH * HT_A];   // 10240 f16 = 20480 B
    __shared__ float sred[16][10];
    _Float16* Iq = Ubuf;                     // [0, 17920 B): 2 x 80 x 56 f16
    _Float16* Tg = Ubuf + 2 * IQ_H;          // [17920, 18944 B): 16 x 32 f16

    const int b  = blockIdx.z;
    const int r0 = blockIdx.y * TH;
    const int c0 = blockIdx.x * TW;
    const float* pb = pred + (size_t)b * NPIX;
    const float* tb = targ + (size_t)b * NPIX;
    const bool interior = (blockIdx.y < 31) && (blockIdx.x < 63);

    // ---- banded Gaussian table (threads 0..15; each owns its row) ----
    if (threadIdx.x < 16) {
        int n = threadIdx.x;
#pragma unroll
        for (int i = 0; i < 16; ++i) ((unsigned*)Tg)[n * 16 + i] = 0u;
#pragma unroll
        for (int j = 0; j < 11; ++j) Tg[n * 32 + n + j] = (_Float16)gw.g[j];
    }

    float s0 = 0.f, s1 = 0.f, s2 = 0.f, s3 = 0.f, ssum = 0.f;
    f32x2 s4v = {0,0}, s5v = {0,0}, s6v = {0,0}, s7v = {0,0}, s8v = {0,0}, ssv = {0,0};

    // ---- stage A: 80 rows x 48 cols staged; core(512) + halo(256+192) ----
    if (interior) {
        // ======== issue phase: 16 raw loads, zero intervening waitcnts ========
        f32x4 cA[2], cB[2], cAD[2], cBD[2];
        float cp5[2], ct5[2];
#pragma unroll
        for (int i = 0; i < 2; ++i) {
            int item = threadIdx.x + i * 256;
            int r = item >> 3, d = item & 7;
            const float* prow = pb + (size_t)(r0 + r) * WDIM + (c0 + d * 4);
            const float* trow = tb + (size_t)(r0 + r) * WDIM + (c0 + d * 4);
            GLOAD4(cA[i], prow);
            GLOAD4(cB[i], trow);
            GLOAD4(cAD[i], prow + WDIM);
            GLOAD4(cBD[i], trow + WDIM);
            GLOAD1(cp5[i], prow + 4);
            GLOAD1(ct5[i], trow + 4);
        }
        f32x4 h0A, h0B, h1A, h1B;
        const int h0r = threadIdx.x >> 2, h0d = 8 + (threadIdx.x & 3);
        {
            const float* prow = pb + (size_t)(r0 + h0r) * WDIM + (c0 + h0d * 4);
            const float* trow = tb + (size_t)(r0 + h0r) * WDIM + (c0 + h0d * 4);
            GLOAD4(h0A, prow);
            GLOAD4(h0B, trow);
        }
        const bool act1 = threadIdx.x < 192;
        const int rq1 = threadIdx.x / 12;
        const int h1r = 64 + rq1, h1d = threadIdx.x - rq1 * 12;
        if (act1) {
            const float* prow = pb + (size_t)(r0 + h1r) * WDIM + (c0 + h1d * 4);
            const float* trow = tb + (size_t)(r0 + h1r) * WDIM + (c0 + h1d * 4);
            GLOAD4(h1A, prow);
            GLOAD4(h1B, trow);
        }
        // single drain for all 16 loads; fence consumers below it
        asm volatile("s_waitcnt vmcnt(0)" ::: "memory");
        __builtin_amdgcn_sched_barrier(0);

        // ======== compute phase (all data in registers) ========
#pragma unroll
        for (int i = 0; i < 2; ++i) {
            int item = threadIdx.x + i * 256;
            int r = item >> 3, d = item & 7;
            f32x4 a4 = cA[i], b4 = cB[i], ad = cAD[i], bd = cBD[i];
            float p5 = cp5[i], t5 = ct5[i];

            f32x2 a01 = {a4.x, a4.y}, a23 = {a4.z, a4.w};
            f32x2 b01 = {b4.x, b4.y}, b23 = {b4.z, b4.w};
            f32x2 dd01 = a01 - b01, dd23 = a23 - b23;
            float dd4 = p5 - t5;
            f32x2 g01 = f32x2{ad.x, ad.y} - f32x2{bd.x, bd.y};
            f32x2 g23 = f32x2{ad.z, ad.w} - f32x2{bd.z, bd.w};

            s0 += fabsf(dd01.x); s0 += fabsf(dd01.y);
            s0 += fabsf(dd23.x); s0 += fabsf(dd23.y);
            s1 += fabsf(dd01.x - g01.x); s1 += fabsf(dd01.y - g01.y);
            s1 += fabsf(dd23.x - g23.x); s1 += fabsf(dd23.y - g23.y);
            s2 += fabsf(dd01.x - dd01.y); s2 += fabsf(dd01.y - dd23.x);
            s2 += fabsf(dd23.x - dd23.y); s2 += fabsf(dd23.y - dd4);
            s3 += fmaxf(fabsf(a4.x) - 1.0f, 0.0f);
            s3 += fmaxf(fabsf(a4.y) - 1.0f, 0.0f);
            s3 += fmaxf(fabsf(a4.z) - 1.0f, 0.0f);
            s3 += fmaxf(fabsf(a4.w) - 1.0f, 0.0f);
            s4v += a01; s4v += a23;
            s5v += b01; s5v += b23;
            s6v += a01 * a01; s6v += a23 * a23;
            s7v += b01 * b01; s7v += b23 * b23;
            f32x2 qp01 = quant2(a01), qp23 = quant2(a23);
            f32x2 qt01 = quant2(b01), qt23 = quant2(b23);
            f32x2 qd01 = qp01 - qt01, qd23 = qp23 - qt23;
            s8v += qd01 * qd01; s8v += qd23 * qd23;

            *(uint2*)&Iq[r * IQ_S + d * 4] =
                make_uint2(pk2(qp01.x, qp01.y), pk2(qp23.x, qp23.y));
            *(uint2*)&Iq[IQ_H + r * IQ_S + d * 4] =
                make_uint2(pk2(qt01.x, qt01.y), pk2(qt23.x, qt23.y));
        }
        // halo 0: rows 0..63, cols 32..47
        {
            f32x2 qp01 = quant2(f32x2{h0A.x, h0A.y}), qp23 = quant2(f32x2{h0A.z, h0A.w});
            f32x2 qt01 = quant2(f32x2{h0B.x, h0B.y}), qt23 = quant2(f32x2{h0B.z, h0B.w});
            *(uint2*)&Iq[h0r * IQ_S + h0d * 4] =
                make_uint2(pk2(qp01.x, qp01.y), pk2(qp23.x, qp23.y));
            *(uint2*)&Iq[IQ_H + h0r * IQ_S + h0d * 4] =
                make_uint2(pk2(qt01.x, qt01.y), pk2(qt23.x, qt23.y));
        }
        // halo 1: rows 64..79, all 12 dword-groups (192 items); h1A/h1B only
        // ever touched under act1 (loads and consumers both guarded)
        if (act1) {
            f32x2 qp01 = quant2(f32x2{h1A.x, h1A.y}), qp23 = quant2(f32x2{h1A.z, h1A.w});
            f32x2 qt01 = quant2(f32x2{h1B.x, h1B.y}), qt23 = quant2(f32x2{h1B.z, h1B.w});
            *(uint2*)&Iq[h1r * IQ_S + h1d * 4] =
                make_uint2(pk2(qp01.x, qp01.y), pk2(qp23.x, qp23.y));
            *(uint2*)&Iq[IQ_H + h1r * IQ_S + h1d * 4] =
                make_uint2(pk2(qt01.x, qt01.y), pk2(qt23.x, qt23.y));
        }
    } else {
        // edge tiles (~4.6% of blocks): guarded path, unchanged
#pragma unroll
        for (int i = 0; i < 2; ++i) {
            int item = threadIdx.x + i * 256;
            int r = item >> 3, d = item & 7;
            int gr = r0 + r, gc = c0 + d * 4;
            const float* prow = pb + (size_t)gr * WDIM + gc;
            const float* trow = tb + (size_t)gr * WDIM + gc;
            float4 a4 = *(const float4*)prow;
            float4 b4 = *(const float4*)trow;
            bool down = gr < (HDIM - 1);
            bool hasR = (gc + 4) < WDIM;
            float4 z4 = make_float4(0.f, 0.f, 0.f, 0.f);
            float4 ad = down ? *(const float4*)(prow + WDIM) : z4;
            float4 bd = down ? *(const float4*)(trow + WDIM) : z4;
            float p5 = hasR ? prow[4] : 0.0f;
            float t5 = hasR ? trow[4] : 0.0f;
            float pv[4] = {a4.x, a4.y, a4.z, a4.w};
            float tv[4] = {b4.x, b4.y, b4.z, b4.w};
            float pd[4] = {ad.x, ad.y, ad.z, ad.w};
            float td[4] = {bd.x, bd.y, bd.z, bd.w};
            float qp[4], qt[4];
#pragma unroll
            for (int k = 0; k < 4; ++k) { qp[k] = quant_u8f(pv[k]); qt[k] = quant_u8f(tv[k]); }
#pragma unroll
            for (int k = 0; k < 4; ++k) {
                float av = pv[k], bv = tv[k];
                float dd = av - bv;
                s0 += fabsf(dd);
                s3 += fmaxf(fabsf(av) - 1.0f, 0.0f);
                s4v.x += av;  s5v.x += bv;
                s6v.x = fmaf(av, av, s6v.x);
                s7v.x = fmaf(bv, bv, s7v.x);
                if (down) s1 += fabsf(dd - (pd[k] - td[k]));
                float nr  = (k < 3) ? pv[k + 1] : p5;
                float nt2 = (k < 3) ? tv[k + 1] : t5;
                if (k < 3 || hasR) s2 += fabsf(dd - (nr - nt2));
                float qd = qp[k] - qt[k];
                s8v.x = fmaf(qd, qd, s8v.x);
            }
            *(uint2*)&Iq[r * IQ_S + d * 4] =
                make_uint2(pk2(qp[0], qp[1]), pk2(qp[2], qp[3]));
            *(uint2*)&Iq[IQ_H + r * IQ_S + d * 4] =
                make_uint2(pk2(qt[0], qt[1]), pk2(qt[2], qt[3]));
        }
#pragma unroll
        for (int ph = 0; ph < 2; ++ph) {
            int r, d;
            bool active = true;
            if (ph == 0) { int h = threadIdx.x; r = h >> 2; d = 8 + (h & 3); }
            else {
                int h = threadIdx.x;
                active = h < 192;
                int rq = h / 12;
                r = 64 + rq; d = h - rq * 12;
            }
            if (active) {
                int gr = r0 + r, gc = c0 + d * 4;
                bool rowok = gr < HDIM;
                const float* prow = pb + (size_t)gr * WDIM + gc;
                const float* trow = tb + (size_t)gr * WDIM + gc;
                float qp[4], qt[4];
                if (rowok && (gc + 3) < WDIM) {
                    float4 a4 = *(const float4*)prow;
                    float4 b4 = *(const float4*)trow;
                    qp[0]=quant_u8f(a4.x); qp[1]=quant_u8f(a4.y); qp[2]=quant_u8f(a4.z); qp[3]=quant_u8f(a4.w);
                    qt[0]=quant_u8f(b4.x); qt[1]=quant_u8f(b4.y); qt[2]=quant_u8f(b4.z); qt[3]=quant_u8f(b4.w);
                } else {
#pragma unroll
                    for (int k = 0; k < 4; ++k) {
                        bool ok = rowok && (gc + k) < WDIM;
                        qp[k] = ok ? quant_u8f(prow[k]) : 0.0f;
                        qt[k] = ok ? quant_u8f(trow[k]) : 0.0f;
                    }
                }
                *(uint2*)&Iq[r * IQ_S + d * 4] =
                    make_uint2(pk2(qp[0], qp[1]), pk2(qp[2], qp[3]));
                *(uint2*)&Iq[IQ_H + r * IQ_S + d * 4] =
                    make_uint2(pk2(qt[0], qt[1]), pk2(qt[2], qt[3]));
            }
        }
    }
    __syncthreads();

    const int lane = threadIdx.x & 63;
    const int wid  = threadIdx.x >> 6;
    const int q    = lane >> 4;
    const int ml   = lane & 15;
    // shared Gaussian fragment: horizontal B-operand == vertical A-operand.
    // Loaded BEFORE the aliasing barrier -- Tg is dead after this.
    const half8 gfrag = *(const half8*)&Tg[ml * 32 + q * 8];
    const f32x4 zero4 = {0.f, 0.f, 0.f, 0.f};
    const _Float16 hquart = (_Float16)0.25f;

    // ---- stage H part 1: preload A-fragments for this wave's positions ----
    const int npos = (wid < 2) ? 3 : 2;
    half8 hap[3], hat[3];
#pragma unroll
    for (int i = 0; i < 3; ++i) {
        if (i < npos) {
            int pos = wid + i * 4;
            int rb = (pos >> 1) * 16;
            int cb = pos & 1;
            int base = (rb + ml) * IQ_S + cb * 16 + q * 8;
            hap[i] = *(const half8*)&Iq[base];
            hat[i] = *(const half8*)&Iq[IQ_H + base];
        }
    }
    __syncthreads();   // all Iq/Tg reads done -> HT may overwrite the union buffer

    // ---- stage H part 2: horizontal conv via MFMA; HT aliases Iq+Tg ----
#pragma unroll
    for (int i = 0; i < 3; ++i) {
        if (i < npos) {
            int pos = wid + i * 4;
            int rb = (pos >> 1) * 16;
            int cb = pos & 1;
            const half8 ap = hap[i];
            const half8 at = hat[i];
            half8 m2 = (ap * hquart) * ap;
            m2 = (at * hquart) * at + m2;
            f32x4 d0 = __builtin_amdgcn_mfma_f32_16x16x32_f16(ap,      gfrag, zero4, 0, 0, 0);
            f32x4 d1 = __builtin_amdgcn_mfma_f32_16x16x32_f16(at,      gfrag, zero4, 0, 0, 0);
            f32x4 d2 = __builtin_amdgcn_mfma_f32_16x16x32_f16(m2,      gfrag, zero4, 0, 0, 0);
            f32x4 d3 = __builtin_amdgcn_mfma_f32_16x16x32_f16(ap * at, gfrag, zero4, 0, 0, 0);
            int hb = (cb * 16 + ml) * HT_R + rb + q * 4;
            *(uint2*)&Ubuf[0 * HT_A + hb] = make_uint2(pk2(d0[0], d0[1]), pk2(d0[2], d0[3]));
            *(uint2*)&Ubuf[1 * HT_A + hb] = make_uint2(pk2(d1[0], d1[1]), pk2(d1[2], d1[3]));
            *(uint2*)&Ubuf[2 * HT_A + hb] = make_uint2(pk2(d2[0], d2[1]), pk2(d2[2], d2[3]));
            *(uint2*)&Ubuf[3 * HT_A + hb] = make_uint2(pk2(d3[0], d3[1]), pk2(d3[2], d3[3]));
        }
    }
    __syncthreads();

    // ---- stage V: vertical conv via MFMA + SSIM map; 8 positions, 2/wave ----
    const int th_ = min(TH, OUTW - r0);
    const int tw_ = min(TW, OUTW - c0);
    for (int vp = wid; vp < 8; vp += 4) {
        int rb2 = (vp >> 1) * 16;
        int cb2 = vp & 1;
        f32x4 acc[NCH];
#pragma unroll
        for (int arr = 0; arr < NCH; ++arr) {
            const half8 bf = *(const half8*)&Ubuf[arr * HT_A +
                                                  (cb2 * 16 + ml) * HT_R + rb2 + q * 8];
            acc[arr] = __builtin_amdgcn_mfma_f32_16x16x32_f16(gfrag, bf, zero4, 0, 0, 0);
        }
        if (interior) {
#pragma unroll
            for (int pp = 0; pp < 2; ++pp) {
                f32x2 mu1 = {acc[0][2*pp], acc[0][2*pp+1]};
                f32x2 mu2 = {acc[1][2*pp], acc[1][2*pp+1]};
                f32x2 h2  = {acc[2][2*pp], acc[2][2*pp+1]};
                f32x2 h12 = {acc[3][2*pp], acc[3][2*pp+1]};
                f32x2 mu12 = mu1 * mu2, mu1s = mu1 * mu1, mu2s = mu2 * mu2;
                f32x2 sg12 = h12 - mu12;
                f32x2 sgs  = 4.0f * h2 - mu1s - mu2s;
                f32x2 num = (2.0f * mu12 + C1F) * (2.0f * sg12 + C2F);
                f32x2 den = (mu1s + mu2s + C1F) * (sgs + C2F);
                f32x2 rp = { __builtin_amdgcn_rcpf(den.x),
                             __builtin_amdgcn_rcpf(den.y) };
                ssv += num * rp;
            }
        } else {
            int col = cb2 * 16 + ml;
#pragma unroll
            for (int reg = 0; reg < 4; ++reg) {
                int row = rb2 + q * 4 + reg;
                if (row < th_ && col < tw_) {
                    float mu1 = acc[0][reg], mu2 = acc[1][reg];
                    float h2  = acc[2][reg], h12 = acc[3][reg];
                    float mu1s = mu1 * mu1, mu2s = mu2 * mu2, mu12 = mu1 * mu2;
                    float sg12 = h12 - mu12;
                    float sgs  = 4.0f * h2 - mu1s - mu2s;
                    float num = (2.0f * mu12 + C1F) * (2.0f * sg12 + C2F);
                    float den = (mu1s + mu2s + C1F) * (sgs + C2F);
                    ssum += num * __builtin_amdgcn_rcpf(den);
                }
            }
        }
    }

    // ---- block reduction: 4-level xor tree within 16-lane groups ----
    float st10[10];
    st10[0] = s0; st10[1] = s1; st10[2] = s2; st10[3] = s3;
    st10[4] = s4v.x + s4v.y; st10[5] = s5v.x + s5v.y;
    st10[6] = s6v.x + s6v.y; st10[7] = s7v.x + s7v.y;
    st10[8] = s8v.x + s8v.y; st10[9] = ssum + ssv.x + ssv.y;
#pragma unroll
    for (int c = 0; c < 10; ++c) {
        float v = st10[c];
        v += __shfl_xor(v, 8);
        v += __shfl_xor(v, 4);
        v += __shfl_xor(v, 2);
        v += __shfl_xor(v, 1);
        st10[c] = v;
    }
    if ((lane & 15) == 0) {
        int g = wid * 4 + (lane >> 4);
#pragma unroll
        for (int c = 0; c < 10; ++c) sred[g][c] = st10[c];
    }
    __syncthreads();
    if (threadIdx.x < 10) {
        int c = threadIdx.x;
        float t = 0.0f;
#pragma unroll
        for (int g = 0; g < 16; ++g) t += sred[g][c];
        int bid = ((b * 32) + blockIdx.y) * 64 + blockIdx.x;
        pr[c * NBLK + bid] = t;
    }
}

// ---------------------------------------------------------------------------
// Final: ONE block. 40 segments of 2048 contiguous floats, coalesced float4
// reads, f64 shfl-reduce; thread 0 does the scalar combine.
// ---------------------------------------------------------------------------
__global__ __launch_bounds__(256) void amsr2_final(
        const float* __restrict__ pr, float* __restrict__ out)
{
    __shared__ double seg[40];
    int wid = threadIdx.x >> 6, lane = threadIdx.x & 63;
    for (int sidx = wid; sidx < 40; sidx += 4) {
        int c = sidx >> 2, b = sidx & 3;
        const float* base = pr + c * NBLK + b * 2048;
        float4 v[8];
#pragma unroll
        for (int it = 0; it < 8; ++it)
            v[it] = *(const float4*)(base + (it * 64 + lane) * 4);
        double acc = 0.0;
#pragma unroll
        for (int it = 0; it < 8; ++it)
            acc += (double)v[it].x + (double)v[it].y + (double)v[it].z + (double)v[it].w;
        for (int off = 32; off > 0; off >>= 1) acc += __shfl_down(acc, off);
        if (lane == 0) seg[sidx] = acc;
    }
    __syncthreads();
    if (threadIdx.x != 0) return;
    const double n = (double)NPIX;
    double sum0 = 0, sum1 = 0, sum2 = 0, sum3 = 0;
    for (int b = 0; b < 4; ++b) {
        sum0 += seg[0*4+b]; sum1 += seg[1*4+b]; sum2 += seg[2*4+b]; sum3 += seg[3*4+b];
    }
    double l1   = sum0 / (4.0 * n);
    double grad = sum1 / (4.0 * 2047.0 * 2048.0) + sum2 / (4.0 * 2048.0 * 2047.0);
    double energy = 0.0, dist = 0.0, psnr_sum = 0.0, ssim_sum = 0.0;
    for (int b = 0; b < 4; ++b) {
        double Sp  = seg[4*4+b],  St  = seg[5*4+b];
        double Spp = seg[6*4+b],  Stt = seg[7*4+b];
        double Su8 = seg[8*4+b],  Sss = seg[9*4+b];
        double pm = Sp / n, tm = St / n;
        double dm = pm - tm; energy += dm * dm;
        double vp = (Spp - n * pm * pm) / (n - 1.0);
        double vt = (Stt - n * tm * tm) / (n - 1.0);
        double ps = sqrt(fmax(vp, 0.0)), ts = sqrt(fmax(vt, 0.0));
        double dd = ps - ts; dist += dd * dd;
        double mse = Su8 / n;
        double psnr = (mse == 0.0) ? 100.0 : 10.0 * log10(65025.0 / fmax(mse, 1e-12));
        psnr_sum += psnr;
        ssim_sum += Sss / ((double)OUTW * (double)OUTW);
    }
    energy *= 0.25; dist *= 0.25;
    double range_pen = sum3 / (4.0 * n);
    double phys = energy + 0.5 * dist + 0.1 * range_pen;
    double ssim_mean = fmin(fmax(ssim_sum * 0.25, 0.0), 1.0);
    double total = l1 + 0.15 * grad + 0.05 * phys + 0.1 * (1.0 - ssim_mean);
    out[0] = (float)total;
    out[1] = (float)(psnr_sum * 0.25);
    out[2] = (float)ssim_mean;
}

extern "C" void kernel_launch(void* const* d_in, const int* in_sizes, int n_in,
                              void* d_out, int out_size, void* d_ws, size_t ws_size,
                              hipStream_t stream)
{
    (void)in_sizes; (void)n_in; (void)out_size; (void)ws_size;
    const float* pred = (const float*)d_in[0];
    const float* targ = (const float*)d_in[1];
    float* out = (float*)d_out;
    float* pr  = (float*)d_ws;            // 10 * 8192 floats of per-block partials

    GaussW gw;                            // host-side f64 Gaussian, cast to f32
    {
        double e[11], sm = 0.0;
        for (int i = 0; i < 11; ++i) {
            double d = (double)(i - 5);
            e[i] = exp(-(d * d) / 4.5);
            sm += e[i];
        }
        for (int i = 0; i < 11; ++i) gw.g[i] = (float)(e[i] / sm);
    }

    amsr2_fused<<<dim3(64, 32, 4), 256, 0, stream>>>(pred, targ, pr, gw);
    amsr2_final<<<1, 256, 0, stream>>>(pr, out);
}